// Round 9
// baseline (232.980 us; speedup 1.0000x reference)
//
#include <hip/hip_runtime.h>
#include <math.h>

// Problem constants (B=8, N=2048, D_IN=D_V=256, H=8, HD=32, D_FF=512)
#define RTOT 16384   // B*N rows
#define NSEQ 2048
#define NHEAD 8
#define HDIM 32
// Q pre-scale: log2(e)/sqrt(256) so S_mfma = S_true*log2e, softmax via exp2
#define QSCALE 0.09017132252479462f
#define QINV (1.0f / QSCALE)

typedef __attribute__((ext_vector_type(8))) short short8;
typedef __attribute__((ext_vector_type(4))) float f32x4;

#define GLOBAL_AS(p) ((__attribute__((address_space(1))) void*)(p))
#define LDS_AS(p) ((__attribute__((address_space(3))) void*)(p))

__device__ __forceinline__ unsigned pack_bf16(float a, float b) {
  unsigned ua = __float_as_uint(a) + 0x8000u;
  unsigned ub = __float_as_uint(b) + 0x8000u;
  return (ua >> 16) | (ub & 0xffff0000u);
}
// truncating pack via byte-perm (positive values; bias cancels in softmax ratio)
__device__ __forceinline__ unsigned pack_bf16_perm(float a, float b) {
  return __builtin_amdgcn_perm(__float_as_uint(b), __float_as_uint(a),
                               0x07060302u);
}
__device__ __forceinline__ ushort bf16_1(float a) {
  return (ushort)((__float_as_uint(a) + 0x8000u) >> 16);
}
__device__ __forceinline__ float bf16_to_f(ushort u) {
  return __uint_as_float(((unsigned)u) << 16);
}

// ---------------- stage0: fused weight-transpose + cvt(y) + ln0(x) ----------------
__global__ __launch_bounds__(256) void stage0_kernel(
    const float* __restrict__ x, const float* __restrict__ y,
    const float* __restrict__ Wq, const float* __restrict__ Wk,
    const float* __restrict__ Wv, const float* __restrict__ W1,
    const float* __restrict__ W2, const float* __restrict__ ln0g,
    const float* __restrict__ ln0b, ushort* __restrict__ Wqt,
    ushort* __restrict__ Wkt, ushort* __restrict__ Wvt,
    ushort* __restrict__ W1t, ushort* __restrict__ W2t,
    ushort* __restrict__ yh, ushort* __restrict__ xh) {
  const int bid = blockIdx.x;
  const int t = threadIdx.x;
  if (bid < 112) {
    const float* W;
    ushort* Wt;
    int K, N, tile;
    if (bid < 16) { W = Wq; Wt = Wqt; K = 256; N = 256; tile = bid; }
    else if (bid < 32) { W = Wk; Wt = Wkt; K = 256; N = 256; tile = bid - 16; }
    else if (bid < 48) { W = Wv; Wt = Wvt; K = 256; N = 256; tile = bid - 32; }
    else if (bid < 80) { W = W1; Wt = W1t; K = 256; N = 512; tile = bid - 48; }
    else { W = W2; Wt = W2t; K = 512; N = 256; tile = bid - 80; }
    const int tn = N >> 6;
    const int k0 = (tile / tn) << 6, n0 = (tile % tn) << 6;
    __shared__ float T[64][65];
#pragma unroll
    for (int i = 0; i < 16; ++i) {
      const int idx = t + i * 256;
      const int r = idx >> 6, c = idx & 63;
      T[r][c] = W[(size_t)(k0 + r) * N + n0 + c];
    }
    __syncthreads();
#pragma unroll
    for (int i = 0; i < 16; ++i) {
      const int idx = t + i * 256;
      const int r = idx >> 6, c = idx & 63;
      Wt[(size_t)(n0 + r) * K + k0 + c] = bf16_1(T[c][r]);
    }
  } else if (bid < 4208) {
    const size_t i = ((size_t)(bid - 112) * 256 + t) * 4;
    const float4 v = *(const float4*)&y[i];
    uint2 pk;
    pk.x = pack_bf16(v.x, v.y);
    pk.y = pack_bf16(v.z, v.w);
    *(uint2*)&yh[i] = pk;
  } else {
    const int lane = t & 63, wave = t >> 6;
    const size_t row = (size_t)(bid - 4208) * 4 + wave;
    const float* xr = x + row * 256;
    float4 v = *(const float4*)&xr[lane * 4];
    float s = v.x + v.y + v.z + v.w;
#pragma unroll
    for (int m = 1; m < 64; m <<= 1) s += __shfl_xor(s, m, 64);
    const float mu = s * (1.0f / 256.0f);
    const float dx = v.x - mu, dy = v.y - mu, dz = v.z - mu, dw = v.w - mu;
    float ss = dx * dx + dy * dy + dz * dz + dw * dw;
#pragma unroll
    for (int m = 1; m < 64; m <<= 1) ss += __shfl_xor(ss, m, 64);
    const float rstd = rsqrtf(ss * (1.0f / 256.0f) + 1e-5f);
    const float4 gv = *(const float4*)&ln0g[lane * 4];
    const float4 bv = *(const float4*)&ln0b[lane * 4];
    uint2 pk;
    pk.x = pack_bf16(dx * rstd * gv.x + bv.x, dy * rstd * gv.y + bv.y);
    pk.y = pack_bf16(dz * rstd * gv.z + bv.z, dw * rstd * gv.w + bv.w);
    *(uint2*)&xh[row * 256 + lane * 4] = pk;
  }
}

// ---------------- LayerNorm over D=256, bf16 output ----------------
__global__ __launch_bounds__(256) void ln_kernel(
    const float* __restrict__ X, const float* __restrict__ g,
    const float* __restrict__ bt, ushort* __restrict__ Yh) {
  const int lane = threadIdx.x & 63;
  const int wave = threadIdx.x >> 6;
  const size_t row = (size_t)blockIdx.x * 4 + wave;
  const float* xr = X + row * 256;
  float4 v = *(const float4*)&xr[lane * 4];
  float s = v.x + v.y + v.z + v.w;
#pragma unroll
  for (int m = 1; m < 64; m <<= 1) s += __shfl_xor(s, m, 64);
  const float mu = s * (1.0f / 256.0f);
  const float dx = v.x - mu, dy = v.y - mu, dz = v.z - mu, dw = v.w - mu;
  float ss = dx * dx + dy * dy + dz * dz + dw * dw;
#pragma unroll
  for (int m = 1; m < 64; m <<= 1) ss += __shfl_xor(ss, m, 64);
  const float rstd = rsqrtf(ss * (1.0f / 256.0f) + 1e-5f);
  const float4 gv = *(const float4*)&g[lane * 4];
  const float4 bv = *(const float4*)&bt[lane * 4];
  uint2 pk;
  pk.x = pack_bf16(dx * rstd * gv.x + bv.x, dy * rstd * gv.y + bv.y);
  pk.y = pack_bf16(dz * rstd * gv.z + bv.z, dw * rstd * gv.w + bv.w);
  *(uint2*)&Yh[row * 256 + lane * 4] = pk;
}

// ---------------- merged QKV GEMM, 128x128 tiles ----------------
// grid (128, 6): which = ny>>1 (0:K 1:V 2:Q), n0 = (ny&1)*128. BK=32, 4 waves.
__global__ __launch_bounds__(256) void qkv_kernel(
    const ushort* __restrict__ xh, const ushort* __restrict__ yh,
    const ushort* __restrict__ Wqt, const ushort* __restrict__ Wkt,
    const ushort* __restrict__ Wvt, const float* __restrict__ bq,
    const float* __restrict__ bk, const float* __restrict__ bv,
    ushort* __restrict__ Qh, ushort* __restrict__ Kh,
    ushort* __restrict__ VhT) {
  __shared__ union UU {
    struct { ushort As[128 * 32]; ushort Bs[128 * 32]; } s;
    ushort Ct[128 * 136];  // V-transpose tile [n_local][m_local]
  } u;
  const int t = threadIdx.x;
  const int lane = t & 63, wave = t >> 6;
  const int l16 = lane & 15, quad = lane >> 4;
  const int row0 = blockIdx.x * 128;
  const int ny = blockIdx.y;
  const int which = ny >> 1;  // 0=K 1=V 2=Q
  const int n0 = (ny & 1) << 7;
  const ushort* A = (which == 2) ? xh : yh;
  const ushort* W = (which == 0) ? Wkt : (which == 1) ? Wvt : Wqt;
  const float* bs = (which == 0) ? bk : (which == 1) ? bv : bq;
  const int mrow = (wave & 1) * 64, ncol = (wave >> 1) * 64;

  const ushort* gA0 = A + (size_t)(row0 + (t >> 2)) * 256 + ((t & 3) << 3);
  const ushort* gA1 = gA0 + (size_t)64 * 256;
  const ushort* gB0 = W + (size_t)(n0 + (t >> 2)) * 256 + ((t & 3) << 3);
  const ushort* gB1 = gB0 + (size_t)64 * 256;
  ushort* lA0 = u.s.As + 8 * t;
  ushort* lA1 = u.s.As + 2048 + 8 * t;
  ushort* lB0 = u.s.Bs + 8 * t;
  ushort* lB1 = u.s.Bs + 2048 + 8 * t;

  f32x4 acc[4][4] = {};
  for (int kc = 0; kc < 256; kc += 32) {
    __builtin_amdgcn_global_load_lds(GLOBAL_AS(gA0 + kc), LDS_AS(lA0), 16, 0, 0);
    __builtin_amdgcn_global_load_lds(GLOBAL_AS(gA1 + kc), LDS_AS(lA1), 16, 0, 0);
    __builtin_amdgcn_global_load_lds(GLOBAL_AS(gB0 + kc), LDS_AS(lB0), 16, 0, 0);
    __builtin_amdgcn_global_load_lds(GLOBAL_AS(gB1 + kc), LDS_AS(lB1), 16, 0, 0);
    __syncthreads();
    short8 af[4], bfr[4];
#pragma unroll
    for (int mi = 0; mi < 4; ++mi)
      af[mi] = *(const short8*)&u.s.As[(mrow + mi * 16 + l16) * 32 + quad * 8];
#pragma unroll
    for (int nj = 0; nj < 4; ++nj)
      bfr[nj] = *(const short8*)&u.s.Bs[(ncol + nj * 16 + l16) * 32 + quad * 8];
#pragma unroll
    for (int mi = 0; mi < 4; ++mi)
#pragma unroll
      for (int nj = 0; nj < 4; ++nj)
        acc[mi][nj] = __builtin_amdgcn_mfma_f32_16x16x32_bf16(
            af[mi], bfr[nj], acc[mi][nj], 0, 0, 0);
    __syncthreads();
  }

  if (which == 1) {
    // V: bias + transpose via LDS, coalesced write to VhT[b*256+n][nseq]
#pragma unroll
    for (int nj = 0; nj < 4; ++nj) {
      const int nloc = ncol + nj * 16 + l16;
      const float bvv = bs[n0 + nloc];
#pragma unroll
      for (int mi = 0; mi < 4; ++mi)
#pragma unroll
        for (int r = 0; r < 4; ++r)
          u.Ct[nloc * 136 + mrow + mi * 16 + quad * 4 + r] =
              bf16_1(acc[mi][nj][r] + bvv);
    }
    __syncthreads();
    const int bb = row0 >> 11, ns0 = row0 & 2047;
#pragma unroll
    for (int i = 0; i < 8; ++i) {
      const int c = t + i * 256;
      const int rr = c >> 4, c8 = (c & 15) << 3;
      *(float4*)&VhT[(size_t)(bb * 256 + n0 + rr) * 2048 + ns0 + c8] =
          *(const float4*)&u.Ct[rr * 136 + c8];
    }
  } else {
#pragma unroll
    for (int nj = 0; nj < 4; ++nj) {
      const int n = n0 + ncol + nj * 16 + l16;
      const float bvv = bs[n];
#pragma unroll
      for (int mi = 0; mi < 4; ++mi) {
#pragma unroll
        for (int r = 0; r < 4; ++r) {
          const size_t m = (size_t)row0 + mrow + mi * 16 + quad * 4 + r;
          const float v = acc[mi][nj][r] + bvv;
          if (which == 2) Qh[m * 256 + n] = bf16_1(v * QSCALE);
          else Kh[m * 256 + n] = bf16_1(v);
        }
      }
    }
  }
}

// ---------------- FFN GEMM: 128xNB tile, BK=32 ----------------
// MODE 2: Ch=bf16(gelu(v)) (FFN1) ; MODE 3: Cf=v+res (FFN2 -> out)
template <int MODE, int NB>
__global__ __launch_bounds__(256) void mgemm_kernel(
    const ushort* __restrict__ A, const ushort* __restrict__ Wt,
    const float* __restrict__ bias, const float* __restrict__ res,
    float* __restrict__ Cf, ushort* __restrict__ Ch, int K, int N) {
  __shared__ ushort As[128 * 32];
  __shared__ ushort Bs[NB * 32];
  const int t = threadIdx.x;
  const int lane = t & 63, wave = t >> 6;
  const int l16 = lane & 15, quad = lane >> 4;
  const int row0 = blockIdx.x * 128;
  const int n0 = blockIdx.y * NB;
  const int NJ = NB / 32;
  const int mrow = (wave & 1) * 64, ncol = (wave >> 1) * (NB / 2);

  const ushort* gA0 = A + (size_t)(row0 + (t >> 2)) * K + ((t & 3) << 3);
  const ushort* gA1 = gA0 + (size_t)64 * K;
  const ushort* gB0 = Wt + (size_t)(n0 + (t >> 2)) * K + ((t & 3) << 3);
  const ushort* gB1 = gB0 + (size_t)64 * K;
  ushort* lA0 = As + 8 * t;
  ushort* lA1 = As + 2048 + 8 * t;
  ushort* lB0 = Bs + 8 * t;
  ushort* lB1 = Bs + 2048 + 8 * t;

  f32x4 acc[4][NB / 32] = {};
  for (int kc = 0; kc < K; kc += 32) {
    __builtin_amdgcn_global_load_lds(GLOBAL_AS(gA0 + kc), LDS_AS(lA0), 16, 0, 0);
    __builtin_amdgcn_global_load_lds(GLOBAL_AS(gA1 + kc), LDS_AS(lA1), 16, 0, 0);
    __builtin_amdgcn_global_load_lds(GLOBAL_AS(gB0 + kc), LDS_AS(lB0), 16, 0, 0);
    if (NB == 128)
      __builtin_amdgcn_global_load_lds(GLOBAL_AS(gB1 + kc), LDS_AS(lB1), 16, 0, 0);
    __syncthreads();
    short8 af[4], bfr[NB / 32];
#pragma unroll
    for (int mi = 0; mi < 4; ++mi)
      af[mi] = *(const short8*)&As[(mrow + mi * 16 + l16) * 32 + quad * 8];
#pragma unroll
    for (int nj = 0; nj < NJ; ++nj)
      bfr[nj] = *(const short8*)&Bs[(ncol + nj * 16 + l16) * 32 + quad * 8];
#pragma unroll
    for (int mi = 0; mi < 4; ++mi)
#pragma unroll
      for (int nj = 0; nj < NJ; ++nj)
        acc[mi][nj] = __builtin_amdgcn_mfma_f32_16x16x32_bf16(
            af[mi], bfr[nj], acc[mi][nj], 0, 0, 0);
    __syncthreads();
  }
#pragma unroll
  for (int nj = 0; nj < NJ; ++nj) {
    const int n = n0 + ncol + nj * 16 + l16;
    const float bvv = bias[n];
#pragma unroll
    for (int mi = 0; mi < 4; ++mi) {
#pragma unroll
      for (int r = 0; r < 4; ++r) {
        const size_t m = (size_t)row0 + mrow + mi * 16 + quad * 4 + r;
        float v = acc[mi][nj][r] + bvv;
        if (MODE == 2) {
          v = 0.5f * v * (1.0f + erff(v * 0.70710678118654752f));
          Ch[m * N + n] = bf16_1(v);
        }
        if (MODE == 3) Cf[m * N + n] = v + res[m * N + n];
      }
    }
  }
}

// ---------------- Flash attention (bf16 MFMA, zero-max, kt-pipelined PV) ----------
// O = Q + softmax(Q K^T / 16) V.  Qh pre-scaled by log2(e)/16 (bf16); residual
// recovered as Qh/QSCALE. PV delayed one kt-iteration: PV(kt-1) MFMAs issue
// alongside exp2(kt) (independent), P dbuf visibility via the top barrier.
__global__ __launch_bounds__(256) void attn_kernel(
    const ushort* __restrict__ Qh, const ushort* __restrict__ Kh,
    const ushort* __restrict__ VhT, float* __restrict__ O) {
  __shared__ ushort Ks[2][64][40];         // 10240 B
  __shared__ ushort Vt[2][32][72];         // 9216 B
  __shared__ ushort Pl[2][4][2][16][72];   // 36864 B [buf][wave][grp]

  const int t = threadIdx.x;
  const int lane = t & 63, wave = t >> 6;
  const int l16 = lane & 15, quad = lane >> 4;
  const int bh = blockIdx.x & 63;
  const int qt = blockIdx.x >> 6;  // 0..15
  const int b = bh >> 3, h = bh & 7;

  const size_t rowQ0 = (size_t)(b * NSEQ + qt * 128 + wave * 32 + l16);
  const short8 qfrag0 = *(const short8*)&Qh[rowQ0 * 256 + h * HDIM + quad * 8];
  const short8 qfrag1 =
      *(const short8*)&Qh[(rowQ0 + 16) * 256 + h * HDIM + quad * 8];
  const short8 ones = {16256, 16256, 16256, 16256,
                       16256, 16256, 16256, 16256};  // bf16 1.0 x8
  const f32x4 zf = {0.f, 0.f, 0.f, 0.f};

  f32x4 o00 = zf, o01 = zf, o10 = zf, o11 = zf;
  f32x4 s0 = zf, s1 = zf;

  // staging coords (cooperative, coalesced): K tile [64][32], V tile [32][64]
  const int kr = t >> 2, kc8 = (t & 3) << 3;
  const int vd = t >> 3, vc8 = (t & 7) << 3;
  const ushort* gK = Kh + ((size_t)(b * NSEQ + kr)) * 256 + h * HDIM + kc8;
  const ushort* gV = VhT + ((size_t)(bh * 32 + vd)) * 2048 + vc8;

  float4 kreg = *(const float4*)gK;
  float4 vreg = *(const float4*)gV;

  short8 vP00, vP01, vP10, vP11;  // V frags carried from prev iter

  for (int kt = 0; kt < 32; ++kt) {
    const int bf = kt & 1;
    *(float4*)&Ks[bf][kr][kc8] = kreg;
    *(float4*)&Vt[bf][vd][vc8] = vreg;
    __syncthreads();  // staging visible; also publishes Pl[bf^1] from kt-1
    if (kt < 31) {    // register prefetch, in flight over compute
      kreg = *(const float4*)(gK + (size_t)(kt + 1) * 64 * 256);
      vreg = *(const float4*)(gV + (kt + 1) * 64);
    }

    // fragments of this tile (consumed to regs; V carried to next iter)
    short8 kf[4];
#pragma unroll
    for (int sub = 0; sub < 4; ++sub)
      kf[sub] = *(const short8*)&Ks[bf][sub * 16 + l16][quad * 8];
    const short8 vN00 = *(const short8*)&Vt[bf][l16][quad * 8];
    const short8 vN01 = *(const short8*)&Vt[bf][l16][32 + quad * 8];
    const short8 vN10 = *(const short8*)&Vt[bf][16 + l16][quad * 8];
    const short8 vN11 = *(const short8*)&Vt[bf][16 + l16][32 + quad * 8];

    // S-MFMAs(kt), both groups
    f32x4 sa0[4], sa1[4];
#pragma unroll
    for (int sub = 0; sub < 4; ++sub)
      sa0[sub] =
          __builtin_amdgcn_mfma_f32_16x16x32_bf16(kf[sub], qfrag0, zf, 0, 0, 0);
#pragma unroll
    for (int sub = 0; sub < 4; ++sub)
      sa1[sub] =
          __builtin_amdgcn_mfma_f32_16x16x32_bf16(kf[sub], qfrag1, zf, 0, 0, 0);

    // PV(kt-1): independent of sa -> overlaps exp2 below
    if (kt > 0) {
      const int pb = bf ^ 1;
      const short8 pf00 = *(const short8*)&Pl[pb][wave][0][l16][quad * 8];
      const short8 pf01 = *(const short8*)&Pl[pb][wave][0][l16][32 + quad * 8];
      const short8 pf10 = *(const short8*)&Pl[pb][wave][1][l16][quad * 8];
      const short8 pf11 = *(const short8*)&Pl[pb][wave][1][l16][32 + quad * 8];
      o00 = __builtin_amdgcn_mfma_f32_16x16x32_bf16(pf00, vP00, o00, 0, 0, 0);
      o00 = __builtin_amdgcn_mfma_f32_16x16x32_bf16(pf01, vP01, o00, 0, 0, 0);
      o01 = __builtin_amdgcn_mfma_f32_16x16x32_bf16(pf00, vP10, o01, 0, 0, 0);
      o01 = __builtin_amdgcn_mfma_f32_16x16x32_bf16(pf01, vP11, o01, 0, 0, 0);
      o10 = __builtin_amdgcn_mfma_f32_16x16x32_bf16(pf10, vP00, o10, 0, 0, 0);
      o10 = __builtin_amdgcn_mfma_f32_16x16x32_bf16(pf11, vP01, o10, 0, 0, 0);
      o11 = __builtin_amdgcn_mfma_f32_16x16x32_bf16(pf10, vP10, o11, 0, 0, 0);
      o11 = __builtin_amdgcn_mfma_f32_16x16x32_bf16(pf11, vP11, o11, 0, 0, 0);
      s0 = __builtin_amdgcn_mfma_f32_16x16x32_bf16(pf00, ones, s0, 0, 0, 0);
      s0 = __builtin_amdgcn_mfma_f32_16x16x32_bf16(pf01, ones, s0, 0, 0, 0);
      s1 = __builtin_amdgcn_mfma_f32_16x16x32_bf16(pf10, ones, s1, 0, 0, 0);
      s1 = __builtin_amdgcn_mfma_f32_16x16x32_bf16(pf11, ones, s1, 0, 0, 0);
    }

    // exp2 + perm-pack(kt) -> Pl[bf]; read next iter after its barrier
#pragma unroll
    for (int sub = 0; sub < 4; ++sub) {
      uint2 pk;
      pk.x = pack_bf16_perm(__builtin_amdgcn_exp2f(sa0[sub][0]),
                            __builtin_amdgcn_exp2f(sa0[sub][1]));
      pk.y = pack_bf16_perm(__builtin_amdgcn_exp2f(sa0[sub][2]),
                            __builtin_amdgcn_exp2f(sa0[sub][3]));
      *(uint2*)&Pl[bf][wave][0][l16][sub * 16 + quad * 4] = pk;
    }
#pragma unroll
    for (int sub = 0; sub < 4; ++sub) {
      uint2 pk;
      pk.x = pack_bf16_perm(__builtin_amdgcn_exp2f(sa1[sub][0]),
                            __builtin_amdgcn_exp2f(sa1[sub][1]));
      pk.y = pack_bf16_perm(__builtin_amdgcn_exp2f(sa1[sub][2]),
                            __builtin_amdgcn_exp2f(sa1[sub][3]));
      *(uint2*)&Pl[bf][wave][1][l16][sub * 16 + quad * 4] = pk;
    }

    vP00 = vN00; vP01 = vN01; vP10 = vN10; vP11 = vN11;
  }

  // drain PV(kt=31): P lives in Pl[1] (own-wave writes -> fence)
  __threadfence_block();
  {
    const short8 pf00 = *(const short8*)&Pl[1][wave][0][l16][quad * 8];
    const short8 pf01 = *(const short8*)&Pl[1][wave][0][l16][32 + quad * 8];
    const short8 pf10 = *(const short8*)&Pl[1][wave][1][l16][quad * 8];
    const short8 pf11 = *(const short8*)&Pl[1][wave][1][l16][32 + quad * 8];
    o00 = __builtin_amdgcn_mfma_f32_16x16x32_bf16(pf00, vP00, o00, 0, 0, 0);
    o00 = __builtin_amdgcn_mfma_f32_16x16x32_bf16(pf01, vP01, o00, 0, 0, 0);
    o01 = __builtin_amdgcn_mfma_f32_16x16x32_bf16(pf00, vP10, o01, 0, 0, 0);
    o01 = __builtin_amdgcn_mfma_f32_16x16x32_bf16(pf01, vP11, o01, 0, 0, 0);
    o10 = __builtin_amdgcn_mfma_f32_16x16x32_bf16(pf10, vP00, o10, 0, 0, 0);
    o10 = __builtin_amdgcn_mfma_f32_16x16x32_bf16(pf11, vP01, o10, 0, 0, 0);
    o11 = __builtin_amdgcn_mfma_f32_16x16x32_bf16(pf10, vP10, o11, 0, 0, 0);
    o11 = __builtin_amdgcn_mfma_f32_16x16x32_bf16(pf11, vP11, o11, 0, 0, 0);
    s0 = __builtin_amdgcn_mfma_f32_16x16x32_bf16(pf00, ones, s0, 0, 0, 0);
    s0 = __builtin_amdgcn_mfma_f32_16x16x32_bf16(pf01, ones, s0, 0, 0, 0);
    s1 = __builtin_amdgcn_mfma_f32_16x16x32_bf16(pf10, ones, s1, 0, 0, 0);
    s1 = __builtin_amdgcn_mfma_f32_16x16x32_bf16(pf11, ones, s1, 0, 0, 0);
  }

  // epilogue: O = Q + oacc/l ; Q routed via Pl[0] (free) wave-private
  __threadfence_block();
  *(short8*)&Pl[0][wave][0][l16][quad * 8] = qfrag0;
  *(short8*)&Pl[0][wave][1][l16][quad * 8] = qfrag1;
  __threadfence_block();
#pragma unroll
  for (int g = 0; g < 2; ++g) {
    const f32x4 oS = g ? s1 : s0;
    const f32x4 oa = g ? o10 : o00;
    const f32x4 ob = g ? o11 : o01;
    const size_t row0 =
        (size_t)(b * NSEQ + qt * 128 + wave * 32 + g * 16 + quad * 4);
#pragma unroll
    for (int r = 0; r < 4; ++r) {
      const float q0 = bf16_to_f(Pl[0][wave][g][quad * 4 + r][l16]) * QINV;
      const float q1 = bf16_to_f(Pl[0][wave][g][quad * 4 + r][16 + l16]) * QINV;
      const float il = 1.0f / oS[r];
      const size_t ro = (row0 + r) * 256 + h * HDIM + l16;
      O[ro] = q0 + oa[r] * il;
      O[ro + 16] = q1 + ob[r] * il;
    }
  }
}

extern "C" void kernel_launch(void* const* d_in, const int* in_sizes, int n_in,
                              void* d_out, int out_size, void* d_ws, size_t ws_size,
                              hipStream_t stream) {
  const float* x = (const float*)d_in[0];
  const float* y = (const float*)d_in[1];
  const float* Wq = (const float*)d_in[2];
  const float* bq = (const float*)d_in[3];
  const float* Wk = (const float*)d_in[4];
  const float* bk = (const float*)d_in[5];
  const float* Wv = (const float*)d_in[6];
  const float* bv = (const float*)d_in[7];
  const float* W1 = (const float*)d_in[8];
  const float* b1 = (const float*)d_in[9];
  const float* W2 = (const float*)d_in[10];
  const float* b2 = (const float*)d_in[11];
  const float* ln0g = (const float*)d_in[12];
  const float* ln0b = (const float*)d_in[13];
  const float* ln1g = (const float*)d_in[14];
  const float* ln1b = (const float*)d_in[15];
  float* out = (float*)d_out;
  char* base = (char*)d_ws;

  const size_t RM = (size_t)RTOT * 256;
  // region0: yh (bf16, stage0->qkv) then overwritten by Ob (fp32, attn out)
  ushort* yh = (ushort*)base;
  float* Ob = (float*)base;
  ushort* Qh = (ushort*)(base + 2 * RM * 4);
  ushort* Kh = (ushort*)(base + 2 * RM * 4 + RM * 2);
  ushort* VhT = (ushort*)(base + 3 * RM * 4);
  ushort* xh = (ushort*)(base + 3 * RM * 4 + RM * 2);  // LN0 out; reused as On
  ushort* Onh = xh;
  ushort* Hidh = Qh;  // [R,512] bf16 overlays Qh+Kh (dead after attn)
  char* wbase = base + 4 * RM * 4;
  ushort* Wqt = (ushort*)wbase;  // [256,256]
  ushort* Wkt = Wqt + 65536;
  ushort* Wvt = Wkt + 65536;
  ushort* W1t = Wvt + 65536;   // [512,256]
  ushort* W2t = W1t + 131072;  // [256,512]

  stage0_kernel<<<8304, 256, 0, stream>>>(x, y, Wq, Wk, Wv, W1, W2, ln0g, ln0b,
                                          Wqt, Wkt, Wvt, W1t, W2t, yh, xh);
  qkv_kernel<<<dim3(128, 6), 256, 0, stream>>>(xh, yh, Wqt, Wkt, Wvt, bq, bk,
                                               bv, Qh, Kh, VhT);
  attn_kernel<<<1024, 256, 0, stream>>>(Qh, Kh, VhT, Ob);
  ln_kernel<<<RTOT / 4, 256, 0, stream>>>(Ob, ln1g, ln1b, Onh);
  mgemm_kernel<2, 128><<<dim3(128, 4), 256, 0, stream>>>(Onh, W1t, b1, nullptr,
                                                         nullptr, Hidh, 256, 512);
  mgemm_kernel<3, 64><<<dim3(128, 4), 256, 0, stream>>>(Hidh, W2t, b2, Ob, out,
                                                        nullptr, 512, 256);
}

// Round 10
// 231.234 us; speedup vs baseline: 1.0076x; 1.0076x over previous
//
#include <hip/hip_runtime.h>
#include <math.h>

// Problem constants (B=8, N=2048, D_IN=D_V=256, H=8, HD=32, D_FF=512)
#define RTOT 16384   // B*N rows
#define NSEQ 2048
#define NHEAD 8
#define HDIM 32
// Q pre-scale: log2(e)/sqrt(256) so S_mfma = S_true*log2e, softmax via exp2
#define QSCALE 0.09017132252479462f
#define QINV (1.0f / QSCALE)

typedef __attribute__((ext_vector_type(8))) short short8;
typedef __attribute__((ext_vector_type(4))) float f32x4;

#define GLOBAL_AS(p) ((__attribute__((address_space(1))) void*)(p))
#define LDS_AS(p) ((__attribute__((address_space(3))) void*)(p))

__device__ __forceinline__ unsigned pack_bf16(float a, float b) {
  unsigned ua = __float_as_uint(a) + 0x8000u;
  unsigned ub = __float_as_uint(b) + 0x8000u;
  return (ua >> 16) | (ub & 0xffff0000u);
}
// truncating pack via byte-perm (positive values; bias cancels in softmax ratio)
__device__ __forceinline__ unsigned pack_bf16_perm(float a, float b) {
  return __builtin_amdgcn_perm(__float_as_uint(b), __float_as_uint(a),
                               0x07060302u);
}
__device__ __forceinline__ ushort bf16_1(float a) {
  return (ushort)((__float_as_uint(a) + 0x8000u) >> 16);
}
__device__ __forceinline__ float bf16_to_f(ushort u) {
  return __uint_as_float(((unsigned)u) << 16);
}

// ---------------- stage0: fused weight-transpose + cvt(y) + ln0(x) ----------------
__global__ __launch_bounds__(256) void stage0_kernel(
    const float* __restrict__ x, const float* __restrict__ y,
    const float* __restrict__ Wq, const float* __restrict__ Wk,
    const float* __restrict__ Wv, const float* __restrict__ W1,
    const float* __restrict__ W2, const float* __restrict__ ln0g,
    const float* __restrict__ ln0b, ushort* __restrict__ Wqt,
    ushort* __restrict__ Wkt, ushort* __restrict__ Wvt,
    ushort* __restrict__ W1t, ushort* __restrict__ W2t,
    ushort* __restrict__ yh, ushort* __restrict__ xh) {
  const int bid = blockIdx.x;
  const int t = threadIdx.x;
  if (bid < 112) {
    const float* W;
    ushort* Wt;
    int K, N, tile;
    if (bid < 16) { W = Wq; Wt = Wqt; K = 256; N = 256; tile = bid; }
    else if (bid < 32) { W = Wk; Wt = Wkt; K = 256; N = 256; tile = bid - 16; }
    else if (bid < 48) { W = Wv; Wt = Wvt; K = 256; N = 256; tile = bid - 32; }
    else if (bid < 80) { W = W1; Wt = W1t; K = 256; N = 512; tile = bid - 48; }
    else { W = W2; Wt = W2t; K = 512; N = 256; tile = bid - 80; }
    const int tn = N >> 6;
    const int k0 = (tile / tn) << 6, n0 = (tile % tn) << 6;
    __shared__ float T[64][65];
#pragma unroll
    for (int i = 0; i < 16; ++i) {
      const int idx = t + i * 256;
      const int r = idx >> 6, c = idx & 63;
      T[r][c] = W[(size_t)(k0 + r) * N + n0 + c];
    }
    __syncthreads();
#pragma unroll
    for (int i = 0; i < 16; ++i) {
      const int idx = t + i * 256;
      const int r = idx >> 6, c = idx & 63;
      Wt[(size_t)(n0 + r) * K + k0 + c] = bf16_1(T[c][r]);
    }
  } else if (bid < 4208) {
    const size_t i = ((size_t)(bid - 112) * 256 + t) * 4;
    const float4 v = *(const float4*)&y[i];
    uint2 pk;
    pk.x = pack_bf16(v.x, v.y);
    pk.y = pack_bf16(v.z, v.w);
    *(uint2*)&yh[i] = pk;
  } else {
    const int lane = t & 63, wave = t >> 6;
    const size_t row = (size_t)(bid - 4208) * 4 + wave;
    const float* xr = x + row * 256;
    float4 v = *(const float4*)&xr[lane * 4];
    float s = v.x + v.y + v.z + v.w;
#pragma unroll
    for (int m = 1; m < 64; m <<= 1) s += __shfl_xor(s, m, 64);
    const float mu = s * (1.0f / 256.0f);
    const float dx = v.x - mu, dy = v.y - mu, dz = v.z - mu, dw = v.w - mu;
    float ss = dx * dx + dy * dy + dz * dz + dw * dw;
#pragma unroll
    for (int m = 1; m < 64; m <<= 1) ss += __shfl_xor(ss, m, 64);
    const float rstd = rsqrtf(ss * (1.0f / 256.0f) + 1e-5f);
    const float4 gv = *(const float4*)&ln0g[lane * 4];
    const float4 bv = *(const float4*)&ln0b[lane * 4];
    uint2 pk;
    pk.x = pack_bf16(dx * rstd * gv.x + bv.x, dy * rstd * gv.y + bv.y);
    pk.y = pack_bf16(dz * rstd * gv.z + bv.z, dw * rstd * gv.w + bv.w);
    *(uint2*)&xh[row * 256 + lane * 4] = pk;
  }
}

// ---------------- LayerNorm over D=256, bf16 output ----------------
__global__ __launch_bounds__(256) void ln_kernel(
    const float* __restrict__ X, const float* __restrict__ g,
    const float* __restrict__ bt, ushort* __restrict__ Yh) {
  const int lane = threadIdx.x & 63;
  const int wave = threadIdx.x >> 6;
  const size_t row = (size_t)blockIdx.x * 4 + wave;
  const float* xr = X + row * 256;
  float4 v = *(const float4*)&xr[lane * 4];
  float s = v.x + v.y + v.z + v.w;
#pragma unroll
  for (int m = 1; m < 64; m <<= 1) s += __shfl_xor(s, m, 64);
  const float mu = s * (1.0f / 256.0f);
  const float dx = v.x - mu, dy = v.y - mu, dz = v.z - mu, dw = v.w - mu;
  float ss = dx * dx + dy * dy + dz * dz + dw * dw;
#pragma unroll
  for (int m = 1; m < 64; m <<= 1) ss += __shfl_xor(ss, m, 64);
  const float rstd = rsqrtf(ss * (1.0f / 256.0f) + 1e-5f);
  const float4 gv = *(const float4*)&g[lane * 4];
  const float4 bv = *(const float4*)&bt[lane * 4];
  uint2 pk;
  pk.x = pack_bf16(dx * rstd * gv.x + bv.x, dy * rstd * gv.y + bv.y);
  pk.y = pack_bf16(dz * rstd * gv.z + bv.z, dw * rstd * gv.w + bv.w);
  *(uint2*)&Yh[row * 256 + lane * 4] = pk;
}

// ---------------- merged QKV GEMM (R8: 128x64 tiles, grid (128,12)) ----------------
__global__ __launch_bounds__(256) void qkv_kernel(
    const ushort* __restrict__ xh, const ushort* __restrict__ yh,
    const ushort* __restrict__ Wqt, const ushort* __restrict__ Wkt,
    const ushort* __restrict__ Wvt, const float* __restrict__ bq,
    const float* __restrict__ bk, const float* __restrict__ bv,
    ushort* __restrict__ Qh, ushort* __restrict__ Kh,
    ushort* __restrict__ VhT) {
  __shared__ union UU {
    struct { ushort As[128 * 32]; ushort Bs[64 * 32]; } s;
    ushort Ct[64 * 136];  // V-transpose tile [n_local][m_local]
  } u;
  const int t = threadIdx.x;
  const int lane = t & 63, wave = t >> 6;
  const int l16 = lane & 15, quad = lane >> 4;
  const int row0 = blockIdx.x * 128;
  const int ny = blockIdx.y;
  const int which = ny >> 2;  // 0=K 1=V 2=Q
  const int n0 = (ny & 3) << 6;
  const ushort* A = (which == 2) ? xh : yh;
  const ushort* W = (which == 0) ? Wkt : (which == 1) ? Wvt : Wqt;
  const float* bs = (which == 0) ? bk : (which == 1) ? bv : bq;
  const int mrow = (wave & 1) * 64, ncol = (wave >> 1) * 32;

  const ushort* gA0 = A + (size_t)(row0 + (t >> 2)) * 256 + ((t & 3) << 3);
  const ushort* gA1 = gA0 + (size_t)64 * 256;
  const ushort* gB = W + (size_t)(n0 + (t >> 2)) * 256 + ((t & 3) << 3);
  ushort* lA0 = u.s.As + 8 * t;
  ushort* lA1 = u.s.As + 2048 + 8 * t;
  ushort* lB = u.s.Bs + 8 * t;

  f32x4 acc[4][2] = {};
  for (int kc = 0; kc < 256; kc += 32) {
    __builtin_amdgcn_global_load_lds(GLOBAL_AS(gA0 + kc), LDS_AS(lA0), 16, 0, 0);
    __builtin_amdgcn_global_load_lds(GLOBAL_AS(gA1 + kc), LDS_AS(lA1), 16, 0, 0);
    __builtin_amdgcn_global_load_lds(GLOBAL_AS(gB + kc), LDS_AS(lB), 16, 0, 0);
    __syncthreads();
    short8 af[4], bfr[2];
#pragma unroll
    for (int mi = 0; mi < 4; ++mi)
      af[mi] = *(const short8*)&u.s.As[(mrow + mi * 16 + l16) * 32 + quad * 8];
#pragma unroll
    for (int nj = 0; nj < 2; ++nj)
      bfr[nj] = *(const short8*)&u.s.Bs[(ncol + nj * 16 + l16) * 32 + quad * 8];
#pragma unroll
    for (int mi = 0; mi < 4; ++mi)
#pragma unroll
      for (int nj = 0; nj < 2; ++nj)
        acc[mi][nj] = __builtin_amdgcn_mfma_f32_16x16x32_bf16(
            af[mi], bfr[nj], acc[mi][nj], 0, 0, 0);
    __syncthreads();
  }

  if (which == 1) {
#pragma unroll
    for (int nj = 0; nj < 2; ++nj) {
      const int nloc = ncol + nj * 16 + l16;
      const float bvv = bs[n0 + nloc];
#pragma unroll
      for (int mi = 0; mi < 4; ++mi)
#pragma unroll
        for (int r = 0; r < 4; ++r)
          u.Ct[nloc * 136 + mrow + mi * 16 + quad * 4 + r] =
              bf16_1(acc[mi][nj][r] + bvv);
    }
    __syncthreads();
    const int bb = row0 >> 11, ns0 = row0 & 2047;
#pragma unroll
    for (int i = 0; i < 4; ++i) {
      const int c = t + i * 256;
      const int rr = c >> 4, c8 = (c & 15) << 3;
      *(float4*)&VhT[(size_t)(bb * 256 + n0 + rr) * 2048 + ns0 + c8] =
          *(const float4*)&u.Ct[rr * 136 + c8];
    }
  } else {
#pragma unroll
    for (int nj = 0; nj < 2; ++nj) {
      const int n = n0 + ncol + nj * 16 + l16;
      const float bvv = bs[n];
#pragma unroll
      for (int mi = 0; mi < 4; ++mi) {
#pragma unroll
        for (int r = 0; r < 4; ++r) {
          const size_t m = (size_t)row0 + mrow + mi * 16 + quad * 4 + r;
          const float v = acc[mi][nj][r] + bvv;
          if (which == 2) Qh[m * 256 + n] = bf16_1(v * QSCALE);
          else Kh[m * 256 + n] = bf16_1(v);
        }
      }
    }
  }
}

// ---------------- FFN GEMM: 128x64 tile, BK=32 (R8) ----------------
template <int MODE>
__global__ __launch_bounds__(256) void mgemm_kernel(
    const ushort* __restrict__ A, const ushort* __restrict__ Wt,
    const float* __restrict__ bias, const float* __restrict__ res,
    float* __restrict__ Cf, ushort* __restrict__ Ch, int K, int N) {
  __shared__ ushort As[128 * 32];
  __shared__ ushort Bs[64 * 32];
  const int t = threadIdx.x;
  const int lane = t & 63, wave = t >> 6;
  const int l16 = lane & 15, quad = lane >> 4;
  const int row0 = blockIdx.x * 128;
  const int n0 = blockIdx.y << 6;
  const int mrow = (wave & 1) * 64, ncol = (wave >> 1) * 32;

  const ushort* gA0 = A + (size_t)(row0 + (t >> 2)) * K + ((t & 3) << 3);
  const ushort* gA1 = gA0 + (size_t)64 * K;
  const ushort* gB = Wt + (size_t)(n0 + (t >> 2)) * K + ((t & 3) << 3);
  ushort* lA0 = As + 8 * t;
  ushort* lA1 = As + 2048 + 8 * t;
  ushort* lB = Bs + 8 * t;

  f32x4 acc[4][2] = {};
  for (int kc = 0; kc < K; kc += 32) {
    __builtin_amdgcn_global_load_lds(GLOBAL_AS(gA0 + kc), LDS_AS(lA0), 16, 0, 0);
    __builtin_amdgcn_global_load_lds(GLOBAL_AS(gA1 + kc), LDS_AS(lA1), 16, 0, 0);
    __builtin_amdgcn_global_load_lds(GLOBAL_AS(gB + kc), LDS_AS(lB), 16, 0, 0);
    __syncthreads();
    short8 af[4], bfr[2];
#pragma unroll
    for (int mi = 0; mi < 4; ++mi)
      af[mi] = *(const short8*)&As[(mrow + mi * 16 + l16) * 32 + quad * 8];
#pragma unroll
    for (int nj = 0; nj < 2; ++nj)
      bfr[nj] = *(const short8*)&Bs[(ncol + nj * 16 + l16) * 32 + quad * 8];
#pragma unroll
    for (int mi = 0; mi < 4; ++mi)
#pragma unroll
      for (int nj = 0; nj < 2; ++nj)
        acc[mi][nj] = __builtin_amdgcn_mfma_f32_16x16x32_bf16(
            af[mi], bfr[nj], acc[mi][nj], 0, 0, 0);
    __syncthreads();
  }
#pragma unroll
  for (int nj = 0; nj < 2; ++nj) {
    const int n = n0 + ncol + nj * 16 + l16;
    const float bvv = bias[n];
#pragma unroll
    for (int mi = 0; mi < 4; ++mi) {
#pragma unroll
      for (int r = 0; r < 4; ++r) {
        const size_t m = (size_t)row0 + mrow + mi * 16 + quad * 4 + r;
        float v = acc[mi][nj][r] + bvv;
        if (MODE == 2) {
          v = 0.5f * v * (1.0f + erff(v * 0.70710678118654752f));
          Ch[m * N + n] = bf16_1(v);
        }
        if (MODE == 3) Cf[m * N + n] = v + res[m * N + n];
      }
    }
  }
}

// ---------------- Flash attention (R8 structure, split grid for visibility) ----------
// O = Q + softmax(Q K^T / 16) V. Zero-max (ratio-invariant), l via ones-MFMA.
// Grid 512 per dispatch: bh = idx&63, qt = (idx>>6) + qt0.
__global__ __launch_bounds__(256) void attn_kernel(
    const ushort* __restrict__ Qh, const ushort* __restrict__ Kh,
    const ushort* __restrict__ VhT, float* __restrict__ O, int qt0) {
  __shared__ ushort Ks[2][64][40];      // 10240 B
  __shared__ ushort Vt[2][32][72];      // 9216 B
  __shared__ ushort Pl[4][2][16][72];   // 18432 B  (per-wave, per-group)

  const int t = threadIdx.x;
  const int lane = t & 63, wave = t >> 6;
  const int l16 = lane & 15, quad = lane >> 4;
  const int bh = blockIdx.x & 63;
  const int qt = (blockIdx.x >> 6) + qt0;  // 0..15
  const int b = bh >> 3, h = bh & 7;

  const size_t rowQ0 = (size_t)(b * NSEQ + qt * 128 + wave * 32 + l16);
  const short8 qfrag0 = *(const short8*)&Qh[rowQ0 * 256 + h * HDIM + quad * 8];
  const short8 qfrag1 =
      *(const short8*)&Qh[(rowQ0 + 16) * 256 + h * HDIM + quad * 8];
  const short8 ones = {16256, 16256, 16256, 16256,
                       16256, 16256, 16256, 16256};  // bf16 1.0 x8
  const f32x4 zf = {0.f, 0.f, 0.f, 0.f};

  f32x4 o00 = zf, o01 = zf, o10 = zf, o11 = zf;
  f32x4 s0 = zf, s1 = zf;

  const int kr = t >> 2, kc8 = (t & 3) << 3;
  const int vd = t >> 3, vc8 = (t & 7) << 3;
  const ushort* gK = Kh + ((size_t)(b * NSEQ + kr)) * 256 + h * HDIM + kc8;
  const ushort* gV = VhT + ((size_t)(bh * 32 + vd)) * 2048 + vc8;

  float4 kreg = *(const float4*)gK;
  float4 vreg = *(const float4*)gV;

  for (int kt = 0; kt < 32; ++kt) {
    const int bf = kt & 1;
    *(float4*)&Ks[bf][kr][kc8] = kreg;
    *(float4*)&Vt[bf][vd][vc8] = vreg;
    __syncthreads();
    if (kt < 31) {
      kreg = *(const float4*)(gK + (size_t)(kt + 1) * 64 * 256);
      vreg = *(const float4*)(gV + (kt + 1) * 64);
    }

    short8 kf[4];
#pragma unroll
    for (int sub = 0; sub < 4; ++sub)
      kf[sub] = *(const short8*)&Ks[bf][sub * 16 + l16][quad * 8];
    const short8 vf00 = *(const short8*)&Vt[bf][l16][quad * 8];
    const short8 vf01 = *(const short8*)&Vt[bf][l16][32 + quad * 8];
    const short8 vf10 = *(const short8*)&Vt[bf][16 + l16][quad * 8];
    const short8 vf11 = *(const short8*)&Vt[bf][16 + l16][32 + quad * 8];

    f32x4 sa0[4], sa1[4];
#pragma unroll
    for (int sub = 0; sub < 4; ++sub)
      sa0[sub] =
          __builtin_amdgcn_mfma_f32_16x16x32_bf16(kf[sub], qfrag0, zf, 0, 0, 0);
#pragma unroll
    for (int sub = 0; sub < 4; ++sub)
      sa1[sub] =
          __builtin_amdgcn_mfma_f32_16x16x32_bf16(kf[sub], qfrag1, zf, 0, 0, 0);

#pragma unroll
    for (int sub = 0; sub < 4; ++sub) {
      uint2 pk;
      pk.x = pack_bf16_perm(__builtin_amdgcn_exp2f(sa0[sub][0]),
                            __builtin_amdgcn_exp2f(sa0[sub][1]));
      pk.y = pack_bf16_perm(__builtin_amdgcn_exp2f(sa0[sub][2]),
                            __builtin_amdgcn_exp2f(sa0[sub][3]));
      *(uint2*)&Pl[wave][0][l16][sub * 16 + quad * 4] = pk;
    }
#pragma unroll
    for (int sub = 0; sub < 4; ++sub) {
      uint2 pk;
      pk.x = pack_bf16_perm(__builtin_amdgcn_exp2f(sa1[sub][0]),
                            __builtin_amdgcn_exp2f(sa1[sub][1]));
      pk.y = pack_bf16_perm(__builtin_amdgcn_exp2f(sa1[sub][2]),
                            __builtin_amdgcn_exp2f(sa1[sub][3]));
      *(uint2*)&Pl[wave][1][l16][sub * 16 + quad * 4] = pk;
    }
    __threadfence_block();

    const short8 pf00 = *(const short8*)&Pl[wave][0][l16][quad * 8];
    const short8 pf01 = *(const short8*)&Pl[wave][0][l16][32 + quad * 8];
    const short8 pf10 = *(const short8*)&Pl[wave][1][l16][quad * 8];
    const short8 pf11 = *(const short8*)&Pl[wave][1][l16][32 + quad * 8];
    o00 = __builtin_amdgcn_mfma_f32_16x16x32_bf16(pf00, vf00, o00, 0, 0, 0);
    o00 = __builtin_amdgcn_mfma_f32_16x16x32_bf16(pf01, vf01, o00, 0, 0, 0);
    o01 = __builtin_amdgcn_mfma_f32_16x16x32_bf16(pf00, vf10, o01, 0, 0, 0);
    o01 = __builtin_amdgcn_mfma_f32_16x16x32_bf16(pf01, vf11, o01, 0, 0, 0);
    o10 = __builtin_amdgcn_mfma_f32_16x16x32_bf16(pf10, vf00, o10, 0, 0, 0);
    o10 = __builtin_amdgcn_mfma_f32_16x16x32_bf16(pf11, vf01, o10, 0, 0, 0);
    o11 = __builtin_amdgcn_mfma_f32_16x16x32_bf16(pf10, vf10, o11, 0, 0, 0);
    o11 = __builtin_amdgcn_mfma_f32_16x16x32_bf16(pf11, vf11, o11, 0, 0, 0);
    s0 = __builtin_amdgcn_mfma_f32_16x16x32_bf16(pf00, ones, s0, 0, 0, 0);
    s0 = __builtin_amdgcn_mfma_f32_16x16x32_bf16(pf01, ones, s0, 0, 0, 0);
    s1 = __builtin_amdgcn_mfma_f32_16x16x32_bf16(pf10, ones, s1, 0, 0, 0);
    s1 = __builtin_amdgcn_mfma_f32_16x16x32_bf16(pf11, ones, s1, 0, 0, 0);
  }

  // epilogue: O = Q + oacc/l ; Q routed via wave-private LDS
  __threadfence_block();
  *(short8*)&Pl[wave][0][l16][quad * 8] = qfrag0;
  *(short8*)&Pl[wave][1][l16][quad * 8] = qfrag1;
  __threadfence_block();
#pragma unroll
  for (int g = 0; g < 2; ++g) {
    const f32x4 oS = g ? s1 : s0;
    const f32x4 oa = g ? o10 : o00;
    const f32x4 ob = g ? o11 : o01;
    const size_t row0 =
        (size_t)(b * NSEQ + qt * 128 + wave * 32 + g * 16 + quad * 4);
#pragma unroll
    for (int r = 0; r < 4; ++r) {
      const float q0 = bf16_to_f(Pl[wave][g][quad * 4 + r][l16]) * QINV;
      const float q1 = bf16_to_f(Pl[wave][g][quad * 4 + r][16 + l16]) * QINV;
      const float il = 1.0f / oS[r];
      const size_t ro = (row0 + r) * 256 + h * HDIM + l16;
      O[ro] = q0 + oa[r] * il;
      O[ro + 16] = q1 + ob[r] * il;
    }
  }
}

extern "C" void kernel_launch(void* const* d_in, const int* in_sizes, int n_in,
                              void* d_out, int out_size, void* d_ws, size_t ws_size,
                              hipStream_t stream) {
  const float* x = (const float*)d_in[0];
  const float* y = (const float*)d_in[1];
  const float* Wq = (const float*)d_in[2];
  const float* bq = (const float*)d_in[3];
  const float* Wk = (const float*)d_in[4];
  const float* bk = (const float*)d_in[5];
  const float* Wv = (const float*)d_in[6];
  const float* bv = (const float*)d_in[7];
  const float* W1 = (const float*)d_in[8];
  const float* b1 = (const float*)d_in[9];
  const float* W2 = (const float*)d_in[10];
  const float* b2 = (const float*)d_in[11];
  const float* ln0g = (const float*)d_in[12];
  const float* ln0b = (const float*)d_in[13];
  const float* ln1g = (const float*)d_in[14];
  const float* ln1b = (const float*)d_in[15];
  float* out = (float*)d_out;
  char* base = (char*)d_ws;

  const size_t RM = (size_t)RTOT * 256;
  ushort* yh = (ushort*)base;
  float* Ob = (float*)base;
  ushort* Qh = (ushort*)(base + 2 * RM * 4);
  ushort* Kh = (ushort*)(base + 2 * RM * 4 + RM * 2);
  ushort* VhT = (ushort*)(base + 3 * RM * 4);
  ushort* xh = (ushort*)(base + 3 * RM * 4 + RM * 2);
  ushort* Onh = xh;
  ushort* Hidh = Qh;
  char* wbase = base + 4 * RM * 4;
  ushort* Wqt = (ushort*)wbase;
  ushort* Wkt = Wqt + 65536;
  ushort* Wvt = Wkt + 65536;
  ushort* W1t = Wvt + 65536;
  ushort* W2t = W1t + 131072;

  stage0_kernel<<<8304, 256, 0, stream>>>(x, y, Wq, Wk, Wv, W1, W2, ln0g, ln0b,
                                          Wqt, Wkt, Wvt, W1t, W2t, yh, xh);
  qkv_kernel<<<dim3(128, 12), 256, 0, stream>>>(xh, yh, Wqt, Wkt, Wvt, bq, bk,
                                                bv, Qh, Kh, VhT);
  attn_kernel<<<512, 256, 0, stream>>>(Qh, Kh, VhT, Ob, 0);
  attn_kernel<<<512, 256, 0, stream>>>(Qh, Kh, VhT, Ob, 8);
  ln_kernel<<<RTOT / 4, 256, 0, stream>>>(Ob, ln1g, ln1b, Onh);
  mgemm_kernel<2><<<dim3(128, 8), 256, 0, stream>>>(Onh, W1t, b1, nullptr,
                                                    nullptr, Hidh, 256, 512);
  mgemm_kernel<3><<<dim3(128, 4), 256, 0, stream>>>(Hidh, W2t, b2, Ob, out,
                                                    nullptr, 512, 256);
}